// Round 15
// baseline (421.772 us; speedup 1.0000x reference)
//
#include <hip/hip_runtime.h>
#include <hip/hip_bf16.h>

#define NNODES 32768
#define NEDGES 524288
#define NGRAPH 512
#define PNODES 64
#define KTOP 30
#define FIN 128
#define HID 256
#define LOUT 27

#define C1F 4.8828125e-4f           // 2^-11
#define C2F 2.384185791015625e-7f   // 2^-22

using f16x8 = __attribute__((ext_vector_type(8))) _Float16;
using f16x4 = __attribute__((ext_vector_type(4))) _Float16;
using f32x4 = __attribute__((ext_vector_type(4))) float;
using f32x16 = __attribute__((ext_vector_type(16))) float;
using u32x4 = __attribute__((ext_vector_type(4))) uint32_t;

template<int N> struct IC { static constexpr int v = N; };

// async global->LDS DMA, 16B per lane, dest = wave-uniform base + lane*16
#define GLDS(src, dst) __builtin_amdgcn_global_load_lds( \
    (const __attribute__((address_space(1))) void*)(src), \
    (__attribute__((address_space(3))) void*)(dst), 16, 0, 0)

// ---------- edge preprocessing ----------
__global__ void hist_kernel(const int* __restrict__ dst, int* __restrict__ counts) {
    int e = blockIdx.x * blockDim.x + threadIdx.x;
    if (e < NEDGES) atomicAdd(&counts[dst[e]], 1);
}

__global__ __launch_bounds__(1024) void scan_block_kernel(const int* __restrict__ counts,
        int* __restrict__ loc, int* __restrict__ partial) {
    int b = blockIdx.x, t = threadIdx.x;
    int i = b * 1024 + t;
    int v = counts[i];
    int lane = t & 63, w = t >> 6;
    int x = v;
    #pragma unroll
    for (int d = 1; d < 64; d <<= 1) { int y = __shfl_up(x, d, 64); if (lane >= d) x += y; }
    __shared__ int ws[16];
    if (lane == 63) ws[w] = x;
    __syncthreads();
    if (w == 0) {
        int s = (lane < 16) ? ws[lane] : 0;
        #pragma unroll
        for (int d = 1; d < 16; d <<= 1) { int y = __shfl_up(s, d, 64); if (lane >= d) s += y; }
        if (lane < 16) ws[lane] = s;
    }
    __syncthreads();
    int base = (w > 0) ? ws[w - 1] : 0;
    int incl = base + x;
    loc[i] = incl - v;
    if (t == 1023) partial[b] = incl;
}

__global__ __launch_bounds__(1024) void scan_fixup_kernel(const int* __restrict__ loc,
        const int* __restrict__ partial, const int* __restrict__ counts,
        int* __restrict__ offsets, int* __restrict__ cursor, float* __restrict__ invdeg) {
    int b = blockIdx.x, t = threadIdx.x;
    int i = b * 1024 + t;
    __shared__ int sbase;
    if (t == 0) { int s = 0; for (int j = 0; j < b; ++j) s += partial[j]; sbase = s; }
    __syncthreads();
    int o = loc[i] + sbase;
    offsets[i] = o;
    cursor[i] = o;
    invdeg[i] = 1.0f / fmaxf((float)counts[i], 1.0f);
}

// ssrc packs (dst_local<<6)|src_local (12 bits) -> direct S-matrix index
__global__ void scatter_kernel(const int* __restrict__ src, const int* __restrict__ dst,
        int* __restrict__ cursor, int* __restrict__ ssrc) {
    int e = blockIdx.x * blockDim.x + threadIdx.x;
    if (e < NEDGES) {
        int d = dst[e];
        int p = atomicAdd(&cursor[d], 1);
        ssrc[p] = ((d & 63) << 6) | (src[e] & 63);
    }
}

// ---------- merged weight/input prep (one launch) ----------
// SAGE weights -> wave-stream fragment order: for wave w, part p (0=Wl,1=Wr),
// chunk (c*2+h2), the 64 lanes' f16x8 fragments are CONTIGUOUS (1KB/chunk).
struct PrepSage {
    const float* src[8];
    _Float16* dh[8];
    _Float16* dl[8];
    int logK[8];
    int part[8];
};

struct PrepAll {
    const float* x;
    _Float16* h0h; _Float16* h0l;
    PrepSage ps;
    const float* convw; _Float16* cvh; _Float16* cvl;
    const float* l1w; _Float16* w1h; _Float16* w1l;
};

// block ranges: [0,4096) nan2num | [4096,6144) sage | [6144,7168) conv | [7168,7600) lin1
__global__ __launch_bounds__(256) void prep_all_kernel(PrepAll P) {
    __shared__ float sh[64][65];
    const int b = blockIdx.x, t = threadIdx.x;
    if (b < 4096) {
        // nan_to_num + split to f16 pair (exact 1,048,576 float4 groups)
        int i = b * 256 + t;
        float4 v = *(const float4*)(P.x + (size_t)i * 4);
        float xs[4] = {v.x, v.y, v.z, v.w};
        f16x4 hh, ll;
        #pragma unroll
        for (int q = 0; q < 4; ++q) {
            float a = xs[q];
            a = (a != a) ? 0.f : a;
            _Float16 h = (_Float16)a;
            hh[q] = h;
            ll[q] = (_Float16)((a - (float)h) * 2048.0f);
        }
        *(f16x4*)(P.h0h + (size_t)i * 4) = hh;
        *(f16x4*)(P.h0l + (size_t)i * 4) = ll;
    } else if (b < 6144) {
        int seg = b - 4096;
        int y = seg >> 8;
        int idx = (seg & 255) * 256 + t;
        int lk = P.ps.logK[y], K = 1 << lk;
        if (idx < 256 * K) {
            int n = idx >> lk, k = idx & (K - 1);
            float w = P.ps.src[y][(size_t)k * 256 + n];
            _Float16 h = (_Float16)w;
            int wv = n >> 5, l31 = n & 31;
            int c = k >> 5, h2 = (k >> 4) & 1, hb = (k >> 3) & 1, j = k & 7;
            int NCH = K >> 5;
            size_t dst = (size_t)(wv * 2 + P.ps.part[y]) * (size_t)(NCH * 1024)
                       + (size_t)(c * 2 + h2) * 512 + (size_t)(hb * 32 + l31) * 8 + j;
            P.ps.dh[y][dst] = h;
            P.ps.dl[y][dst] = (_Float16)((w - (float)h) * 2048.0f);
        }
    } else if (b < 7168) {
        // conv1d weight (o, i, tap) -> [o][k=tap*256+i] split
        int idx = (b - 6144) * 256 + t;
        int o = idx >> 10, k = idx & 1023;
        float w = P.convw[(size_t)o * 1024 + (k & 255) * 4 + (k >> 8)];
        _Float16 h = (_Float16)w;
        P.cvh[(size_t)o * 1024 + k] = h;
        P.cvl[(size_t)o * 1024 + k] = (_Float16)((w - (float)h) * 2048.0f);
    } else {
        // lin1_w [(c*27+l)][n] -> [n][k=l*256+c] f16 split via LDS transpose
        int seg = b - 7168;
        int kb = (seg % 108) * 64;
        int nb = (seg / 108) * 64;
        {
            int kk = t >> 2;
            int nc = (t & 3) * 16;
            int k = kb + kk, l = k >> 8, c = k & 255;
            const float* srow = P.l1w + (size_t)(c * 27 + l) * 256 + nb + nc;
            #pragma unroll
            for (int j = 0; j < 16; j += 4) {
                float4 v = *(const float4*)(srow + j);
                sh[kk][nc + j + 0] = v.x;
                sh[kk][nc + j + 1] = v.y;
                sh[kk][nc + j + 2] = v.z;
                sh[kk][nc + j + 3] = v.w;
            }
        }
        __syncthreads();
        {
            int nn = t >> 2;
            int kc = (t & 3) * 16;
            f16x8 oh[2], ol[2];
            #pragma unroll
            for (int j = 0; j < 16; ++j) {
                float x = sh[kc + j][nn];
                _Float16 h = (_Float16)x;
                oh[j >> 3][j & 7] = h;
                ol[j >> 3][j & 7] = (_Float16)((x - (float)h) * 2048.0f);
            }
            size_t o = (size_t)(nb + nn) * 6912 + kb + kc;
            *(f16x8*)(P.w1h + o) = oh[0];
            *(f16x8*)(P.w1h + o + 8) = oh[1];
            *(f16x8*)(P.w1l + o) = ol[0];
            *(f16x8*)(P.w1l + o + 8) = ol[1];
        }
    }
}

// ---------- fused SAGE: ALL 4 LAYERS + sort-pool/top-k, one graph per block ----------
// v15 fused kernel = v14 VERBATIM (session best: 179us, zero spill, FETCH
// 19.3MB / WRITE 15.4MB). The unroll-4 window was the spill fix. Do not touch.
struct SageWAll {
    const _Float16* wh[4];
    const _Float16* wl[4];
    const float* bias[4];
};

__global__ __launch_bounds__(512, 2) void fused_sage_all_kernel(
        const _Float16* __restrict__ hh, const _Float16* __restrict__ hl,
        const int* __restrict__ offsets, const int* __restrict__ counts,
        const int* __restrict__ ssrc, const float* __restrict__ invdeg,
        SageWAll W,
        _Float16* __restrict__ tkh, _Float16* __restrict__ tkl) {
    __shared__ __align__(16) _Float16 hp[2][8 * 2048];   // 64 KB h tile (pair)
    __shared__ __align__(16) uint32_t Sw[4096];          // 16 KB counts -> S pair -> sortpool scratch
    const int g = blockIdx.x, t = threadIdx.x;
    const int lane = t & 63, wave = t >> 6;
    const int l31 = lane & 31, hb = lane >> 5;

    // zero S counts
    #pragma unroll
    for (int i = 0; i < 8; ++i) Sw[t + i * 512] = 0;

    // stage h0 (64x128 pair) into chunks 0..3: linear LDS dest, swizzled source
    {
        int a = lane >> 2, b = lane & 3;
        #pragma unroll
        for (int u0 = 0; u0 < 4; ++u0) {
            int u = u0 * 8 + wave;
            int part = u & 1;
            int cs = u >> 1;
            int c = cs >> 2, stripe = cs & 3;
            int row = stripe * 16 + a;
            int o = b ^ ((row >> 1) & 3) ^ (c & 3);
            const _Float16* src = (part ? hl : hh) + (size_t)g * (64 * FIN)
                                + (size_t)row * FIN + c * 32 + o * 8;
            GLDS(src, &hp[part][c * 2048 + stripe * 512]);
        }
    }
    const int gbeg = offsets[g * 64];
    const int gend = offsets[g * 64 + 63] + counts[g * 64 + 63];
    __syncthreads();   // Sw zeroed visible; hp DMA drained

    // build adjacency counts (edge-parallel, ~2 iters)
    for (int e = gbeg + t; e < gend; e += 512)
        atomicAdd(&Sw[ssrc[e] & 4095], 1u);
    __syncthreads();

    // counts -> S pair (aliased over Sw): thread = (row d, octet o)
    {
        int d = t >> 3, o = t & 7;
        float idg = invdeg[g * 64 + d];
        float v[8];
        #pragma unroll
        for (int j = 0; j < 8; ++j) v[j] = (float)Sw[(d << 6) + (o << 3) + j] * idg;
        __syncthreads();
        _Float16* Sp = (_Float16*)Sw;
        f16x8 s0, s1;
        #pragma unroll
        for (int j = 0; j < 8; ++j) {
            _Float16 h1 = (_Float16)v[j];
            s0[j] = h1;
            s1[j] = (_Float16)((v[j] - (float)h1) * 2048.0f);
        }
        int addr = (d << 6) + ((o ^ (d & 7)) << 3);
        *(f16x8*)&Sp[addr] = s0;
        *(f16x8*)&Sp[4096 + addr] = s1;
    }
    __syncthreads();

    const int col = (wave << 5) + l31;

    // one 32-row-half split-pair GEMM over K = NCH*32; depth-2 B prefetch,
    // unroll-4 (bounded scheduler window). Returns folded (a0 + 2^-11 * a1).
    auto gemmHalf = [&](auto NC, const _Float16* __restrict__ Bh,
                        const _Float16* __restrict__ Bl, int rowOff) -> f32x16 {
        constexpr int NIT = decltype(NC)::v * 2;
        const int lo8 = lane << 3;
        f32x16 a0 = 0.f, a1 = 0.f;
        f16x8 bhN = *(const f16x8*)(Bh + lo8);
        f16x8 blN = *(const f16x8*)(Bl + lo8);
        #pragma unroll 4
        for (int it = 0; it < NIT; ++it) {
            const int c = it >> 1, h2 = it & 1;
            f16x8 bh = bhN, bl = blN;
            if (it + 1 < NIT) {
                bhN = *(const f16x8*)(Bh + (it + 1) * 512 + lo8);
                blN = *(const f16x8*)(Bl + (it + 1) * 512 + lo8);
            }
            const int slot = (2 * h2 + hb) ^ ((l31 >> 1) & 3) ^ (c & 3);
            const int addr = rowOff + c * 2048 + (l31 << 5) + (slot << 3);
            f16x8 ah = *(const f16x8*)&hp[0][addr];
            f16x8 al = *(const f16x8*)&hp[1][addr];
            a0 = __builtin_amdgcn_mfma_f32_32x32x16_f16(ah, bh, a0, 0, 0, 0);
            a1 = __builtin_amdgcn_mfma_f32_32x32x16_f16(al, bh, a1, 0, 0, 0);
            a1 = __builtin_amdgcn_mfma_f32_32x32x16_f16(ah, bl, a1, 0, 0, 0);
        }
        return a0 + C1F * a1;
    };

    // pack two floats into hi/lo split-f16 words (bit_cast, no unions)
    auto packpair = [](float x, float y, uint32_t& hw, uint32_t& lw) {
        _Float16 xh = (_Float16)x, yh = (_Float16)y;
        _Float16 xl = (_Float16)((x - (float)xh) * 2048.0f);
        _Float16 yl = (_Float16)((y - (float)yh) * 2048.0f);
        hw = (uint32_t)__builtin_bit_cast(unsigned short, xh)
           | ((uint32_t)__builtin_bit_cast(unsigned short, yh) << 16);
        lw = (uint32_t)__builtin_bit_cast(unsigned short, xl)
           | ((uint32_t)__builtin_bit_cast(unsigned short, yl) << 16);
    };

    // one S.P row-half pass: qf += S[rows]·P (B-frags assembled from pf in-reg)
    auto spass = [&](int soffBase, const f32x16& pf0, const f32x16& pf1, f32x16& qf) {
        const _Float16* Sp = (const _Float16*)Sw;
        f32x16 sA = 0.f, sB = 0.f;
        #pragma unroll
        for (int kc = 0; kc < 4; ++kc) {
            const f32x16& pfk = (kc < 2) ? pf0 : pf1;
            const int i0 = ((2 * kc) & 3) * 4, i1 = ((2 * kc + 1) & 3) * 4;
            float kv0 = hb ? pfk[i1 + 0] : pfk[i0 + 0];
            float kv1 = hb ? pfk[i1 + 1] : pfk[i0 + 1];
            float kv2 = hb ? pfk[i1 + 2] : pfk[i0 + 2];
            float kv3 = hb ? pfk[i1 + 3] : pfk[i0 + 3];
            float sv0 = hb ? pfk[i0 + 0] : pfk[i1 + 0];
            float sv1 = hb ? pfk[i0 + 1] : pfk[i1 + 1];
            float sv2 = hb ? pfk[i0 + 2] : pfk[i1 + 2];
            float sv3 = hb ? pfk[i0 + 3] : pfk[i1 + 3];
            uint32_t kh0, kl0, kh1, kl1, sh0, sl0, sh1, sl1;
            packpair(kv0, kv1, kh0, kl0);
            packpair(kv2, kv3, kh1, kl1);
            packpair(sv0, sv1, sh0, sl0);
            packpair(sv2, sv3, sh1, sl1);
            uint32_t rh0 = (uint32_t)__shfl_xor((int)sh0, 32, 64);
            uint32_t rh1 = (uint32_t)__shfl_xor((int)sh1, 32, 64);
            uint32_t rl0 = (uint32_t)__shfl_xor((int)sl0, 32, 64);
            uint32_t rl1 = (uint32_t)__shfl_xor((int)sl1, 32, 64);
            u32x4 bhu, blu;
            bhu[0] = hb ? rh0 : kh0;  bhu[1] = hb ? rh1 : kh1;
            bhu[2] = hb ? kh0 : rh0;  bhu[3] = hb ? kh1 : rh1;
            blu[0] = hb ? rl0 : kl0;  blu[1] = hb ? rl1 : kl1;
            blu[2] = hb ? kl0 : rl0;  blu[3] = hb ? kl1 : rl1;
            f16x8 bhv = __builtin_bit_cast(f16x8, bhu);
            f16x8 blv = __builtin_bit_cast(f16x8, blu);
            int soff = soffBase + (l31 << 6) + (((2 * kc + hb) ^ (l31 & 7)) << 3);
            f16x8 s0a = *(const f16x8*)&Sp[soff];
            f16x8 s1a = *(const f16x8*)&Sp[4096 + soff];
            sA = __builtin_amdgcn_mfma_f32_32x32x16_f16(s0a, bhv, sA, 0, 0, 0);
            sB = __builtin_amdgcn_mfma_f32_32x32x16_f16(s0a, blv, sB, 0, 0, 0);
            sB = __builtin_amdgcn_mfma_f32_32x32x16_f16(s1a, bhv, sB, 0, 0, 0);
        }
        qf += sA + C1F * sB;
    };

    // one SAGE layer: {sC0,sC1} = relu(S·(H·Wl) + H·Wr + b) for my 32-col slice
    auto run_layer = [&](auto NC, const _Float16* __restrict__ Wsh,
                         const _Float16* __restrict__ Wsl,
                         const float* __restrict__ bias,
                         f32x16& sC0, f32x16& sC1) {
        constexpr size_t wstride = (size_t)decltype(NC)::v * 1024;
        const _Float16* BqH = Wsh + (size_t)((wave << 1) + 1) * wstride;
        const _Float16* BqL = Wsl + (size_t)((wave << 1) + 1) * wstride;
        const _Float16* BpH = Wsh + (size_t)(wave << 1) * wstride;
        const _Float16* BpL = Wsl + (size_t)(wave << 1) * wstride;
        // Q = H·Wr (folded per half)
        f32x16 qf0 = gemmHalf(NC, BqH, BqL, 0);
        f32x16 qf1 = gemmHalf(NC, BqH, BqL, 1024);
        // P = H·Wl (folded per half)
        f32x16 pf0 = gemmHalf(NC, BpH, BpL, 0);
        f32x16 pf1 = gemmHalf(NC, BpH, BpL, 1024);
        // S·P folded straight into qf
        spass(0, pf0, pf1, qf0);        // rows 0..31
        spass(2048, pf0, pf1, qf1);     // rows 32..63
        const float bb = bias[col];
        #pragma unroll
        for (int reg = 0; reg < 16; ++reg) {
            sC0[reg] = fmaxf(qf0[reg] + bb, 0.f);
            sC1[reg] = fmaxf(qf1[reg] + bb, 0.f);
        }
    };

    // re-split sC back into hp as chunk c=wave (input layout for next layer)
    auto hp_write = [&](const f32x16& sC0, const f32x16& sC1) {
        int oc = l31 >> 3, j = l31 & 7;
        #pragma unroll
        for (int mi = 0; mi < 2; ++mi)
            #pragma unroll
            for (int reg = 0; reg < 16; ++reg) {
                int row = (mi << 5) + (reg & 3) + ((reg >> 2) << 3) + (hb << 2);
                int slot = oc ^ ((row >> 1) & 3) ^ (wave & 3);
                int addr = wave * 2048 + (row << 5) + (slot << 3) + j;
                float v = mi ? sC1[reg] : sC0[reg];
                _Float16 h1 = (_Float16)v;
                hp[0][addr] = h1;
                hp[1][addr] = (_Float16)((v - (float)h1) * 2048.0f);
            }
    };

    f32x16 sC0, sC1;
    // layer 0 (K=128)
    run_layer(IC<4>{}, W.wh[0], W.wl[0], W.bias[0], sC0, sC1);
    __syncthreads();   // all reads of hp chunks 0..3 done
    hp_write(sC0, sC1);
    __syncthreads();
    // layer 1 (K=256)
    run_layer(IC<8>{}, W.wh[1], W.wl[1], W.bias[1], sC0, sC1);
    __syncthreads();
    hp_write(sC0, sC1);
    __syncthreads();
    // layer 2 (K=256)
    run_layer(IC<8>{}, W.wh[2], W.wl[2], W.bias[2], sC0, sC1);
    __syncthreads();
    hp_write(sC0, sC1);
    __syncthreads();
    // layer 3 (K=256) + fused sort-pool/top-k epilogue
    run_layer(IC<8>{}, W.wh[3], W.wl[3], W.bias[3], sC0, sC1);
    __syncthreads();   // all waves done reading hp + Sw

    // stage h4 (hi -> hp[0], lo -> hp[1]) as [row][col^swz] f16
    #pragma unroll
    for (int mi = 0; mi < 2; ++mi) {
        #pragma unroll
        for (int reg = 0; reg < 16; ++reg) {
            int row = (mi << 5) + (reg & 3) + ((reg >> 2) << 3) + (hb << 2);
            int cx = col ^ ((((row >> 2) & 1) << 5) | ((row & 3) << 3));
            float v = mi ? sC1[reg] : sC0[reg];
            _Float16 h1 = (_Float16)v;
            hp[0][(row << 8) + cx] = h1;
            hp[1][(row << 8) + cx] = (_Float16)((v - (float)h1) * 2048.0f);
        }
    }
    __syncthreads();

    // sort key = channel 255 of each row (from the stored f16 pair — matches
    // the old sortgather exactly)
    float* vals = (float*)Sw;          // Sw dead after last S·P pass
    int* ords = (int*)(Sw + 64);
    if (t < 64) {
        int sx = 255 ^ ((((t >> 2) & 1) << 5) | ((t & 3) << 3));
        vals[t] = (float)hp[0][(t << 8) + sx] + C1F * (float)hp[1][(t << 8) + sx];
    }
    __syncthreads();
    if (t < 64) {
        float v = vals[t];
        int rank = 0;
        for (int j = 0; j < 64; ++j) {
            float vj = vals[j];
            rank += (vj > v) || (vj == v && j < t);
        }
        if (rank < KTOP) ords[rank] = t;
    }
    __syncthreads();
    // gather top-30 rows straight to tk (f16 pair copied verbatim)
    for (int r = wave; r < KTOP; r += 8) {
        int row = ords[r];
        int cc = (lane & 31) << 3;
        int sx = cc ^ ((((row >> 2) & 1) << 5) | ((row & 3) << 3));
        size_t d = (size_t)(g * KTOP + r) * HID + cc;
        if (lane < 32) *(f16x8*)(tkh + d) = *(const f16x8*)&hp[0][(row << 8) + sx];
        else           *(f16x8*)(tkl + d) = *(const f16x8*)&hp[1][(row << 8) + sx];
    }
}

// ---------- pre-split MFMA GEMM (tail: conv1d-as-GEMM, lin1) ----------
template<int NPROD, int CONV, int NPAIRS, int EPI>
__global__ __launch_bounds__(256, 2) void mfma_ps_kernel(
        const _Float16* __restrict__ A1h, const _Float16* __restrict__ A1l,
        const _Float16* __restrict__ A2h, const _Float16* __restrict__ A2l,
        const _Float16* __restrict__ B1h, const _Float16* __restrict__ B1l,
        const _Float16* __restrict__ B2h, const _Float16* __restrict__ B2l,
        const float* __restrict__ bias,
        _Float16* __restrict__ outh, _Float16* __restrict__ outl,
        float* __restrict__ Cpart,
        int lda, int K, int Nd, int nrb) {
    __shared__ _Float16 As[2][2][128 * 32];   // [buf][term][swizzled 8KB]
    __shared__ _Float16 Bs[2][2][128 * 32];
    const int t = threadIdx.x;
    const int lane = t & 63, wave = t >> 6;
    const int wr = wave & 1, wc = wave >> 1;
    const int bid = blockIdx.x;
    const int rb = bid % nrb, cb = bid / nrb;
    const int row0 = rb * 128, col0 = cb * 128;
    const int l31 = lane & 31, hb = lane >> 5, x3 = l31 & 3;
    const int r16 = lane >> 2;
    const int qsrc8 = ((lane & 3) ^ (r16 & 3)) * 8;   // source k-granule (elems)
    size_t aoffj[2], boffj[2];
    #pragma unroll
    for (int j = 0; j < 2; ++j) {
        int ar = row0 + wave * 32 + j * 16 + r16;
        aoffj[j] = CONV ? ((size_t)ar * 256 + (size_t)(ar / 27) * 768)
                        : (size_t)ar * (size_t)lda;
        boffj[j] = (size_t)(col0 + wave * 32 + j * 16 + r16) * (size_t)K;
    }
    int aroff[2], broff[2], slot8[2];
    #pragma unroll
    for (int mi = 0; mi < 2; ++mi) aroff[mi] = (wr * 64 + mi * 32 + l31) * 32;
    #pragma unroll
    for (int ni = 0; ni < 2; ++ni) broff[ni] = (wc * 64 + ni * 32 + l31) * 32;
    #pragma unroll
    for (int h = 0; h < 2; ++h) slot8[h] = ((2 * h + hb) ^ x3) * 8;

    const int KV = NPAIRS * K;
    const int kchunk = KV / gridDim.z;
    const int kv_lo = blockIdx.z * kchunk, kv_hi = kv_lo + kchunk;

    f32x16 acc0[2][2], acc1[2][2], acc2[2][2];
    #pragma unroll
    for (int i = 0; i < 2; ++i)
        #pragma unroll
        for (int j = 0; j < 2; ++j) { acc0[i][j] = 0.f; acc1[i][j] = 0.f; acc2[i][j] = 0.f; }

    auto stage = [&](int kv, int b) {
        int p = (NPAIRS == 2 && kv >= K) ? 1 : 0;
        int k = kv - p * K;
        const _Float16* __restrict__ sAh = p ? A2h : A1h;
        const _Float16* __restrict__ sAl = p ? A2l : A1l;
        const _Float16* __restrict__ sBh = p ? B2h : B1h;
        const _Float16* __restrict__ sBl = p ? B2l : B1l;
        #pragma unroll
        for (int j = 0; j < 2; ++j) {
            int ldsbase = (wave * 32 + j * 16) * 32;   // elems
            size_t ga = aoffj[j] + k + qsrc8;
            size_t gb = boffj[j] + k + qsrc8;
            GLDS(sAh + ga, &As[b][0][ldsbase]);
            GLDS(sAl + ga, &As[b][1][ldsbase]);
            GLDS(sBh + gb, &Bs[b][0][ldsbase]);
            GLDS(sBl + gb, &Bs[b][1][ldsbase]);
        }
    };

    stage(kv_lo, 0);
    __syncthreads();
    int b = 0;
    for (int kv = kv_lo; kv < kv_hi; kv += 32) {
        if (kv + 32 < kv_hi) stage(kv + 32, b ^ 1);
        #pragma unroll
        for (int h = 0; h < 2; ++h) {
            f16x8 af0[2], af1[2], bf0[2], bf1[2];
            #pragma unroll
            for (int mi = 0; mi < 2; ++mi) {
                af0[mi] = *(const f16x8*)&As[b][0][aroff[mi] + slot8[h]];
                af1[mi] = *(const f16x8*)&As[b][1][aroff[mi] + slot8[h]];
            }
            #pragma unroll
            for (int ni = 0; ni < 2; ++ni) {
                bf0[ni] = *(const f16x8*)&Bs[b][0][broff[ni] + slot8[h]];
                bf1[ni] = *(const f16x8*)&Bs[b][1][broff[ni] + slot8[h]];
            }
            #pragma unroll
            for (int mi = 0; mi < 2; ++mi)
                #pragma unroll
                for (int ni = 0; ni < 2; ++ni) {
                    acc0[mi][ni] = __builtin_amdgcn_mfma_f32_32x32x16_f16(af0[mi], bf0[ni], acc0[mi][ni], 0, 0, 0);
                    acc1[mi][ni] = __builtin_amdgcn_mfma_f32_32x32x16_f16(af1[mi], bf0[ni], acc1[mi][ni], 0, 0, 0);
                    acc1[mi][ni] = __builtin_amdgcn_mfma_f32_32x32x16_f16(af0[mi], bf1[ni], acc1[mi][ni], 0, 0, 0);
                    if (NPROD == 4)
                        acc2[mi][ni] = __builtin_amdgcn_mfma_f32_32x32x16_f16(af1[mi], bf1[ni], acc2[mi][ni], 0, 0, 0);
                }
        }
        b ^= 1;
        __syncthreads();   // prefetch DMA landed during compute; reads done before overwrite
    }

    // C/D: col = lane&31, row = (reg&3) + 8*(reg>>2) + 4*(lane>>5)  [m74/m101]
    const int rquad = 4 * hb;
    #pragma unroll
    for (int ni = 0; ni < 2; ++ni) {
        int col = col0 + wc * 64 + ni * 32 + l31;
        float bb = (EPI == 0) ? bias[col] : 0.f;
        #pragma unroll
        for (int mi = 0; mi < 2; ++mi) {
            #pragma unroll
            for (int reg = 0; reg < 16; ++reg) {
                float v = acc0[mi][ni][reg] + C1F * acc1[mi][ni][reg];
                if (NPROD == 4) v += C2F * acc2[mi][ni][reg];
                int row = row0 + wr * 64 + mi * 32 + (reg & 3) + 8 * (reg >> 2) + rquad;
                if (EPI == 0) {
                    v = fmaxf(v + bb, 0.f);
                    _Float16 h = (_Float16)v;
                    size_t o = (size_t)row * Nd + col;
                    outh[o] = h;
                    outl[o] = (_Float16)((v - (float)h) * 2048.0f);
                } else {
                    size_t zb = (size_t)blockIdx.z * (size_t)(nrb * 128) * Nd;
                    Cpart[zb + (size_t)row * Nd + col] = v;
                }
            }
        }
    }
}

// ---------- lin1 reduce (27 partials) ----------
__global__ void reduce_lin1_kernel(const float* __restrict__ z1p,
        const float* __restrict__ b, float* __restrict__ z1) {
    int i = blockIdx.x * 256 + threadIdx.x;   // 131072
    float s = b[i & 255];
    #pragma unroll
    for (int z = 0; z < 27; ++z) s += z1p[(size_t)z * 131072 + i];
    z1[i] = fmaxf(s, 0.f);
}

// ---------- f32 64x64 GEMM (lin2 only) ----------
__global__ __launch_bounds__(256) void gemm64_kernel(
        const float* __restrict__ A, const float* __restrict__ B,
        const float* __restrict__ bias, float* __restrict__ C,
        int lda, int kend, int Nd) {
    __shared__ float As[16][64];
    __shared__ float Bs[16][64];
    const int tid = threadIdx.x;
    const int tx = tid & 15, ty = tid >> 4;
    const int la_r = tid >> 2, la_c = (tid & 3) << 2;
    const int lb_r = tid >> 4, lb_c = (tid & 15) << 2;
    const int row0 = blockIdx.x * 64, col0 = blockIdx.y * 64;
    const size_t aoff = (size_t)(row0 + la_r) * (size_t)lda;
    float acc[4][4] = {};
    for (int k0 = 0; k0 < kend; k0 += 16) {
        __syncthreads();
        float4 av = *(const float4*)(A + aoff + k0 + la_c);
        As[la_c + 0][la_r] = av.x;
        As[la_c + 1][la_r] = av.y;
        As[la_c + 2][la_r] = av.z;
        As[la_c + 3][la_r] = av.w;
        *(float4*)&Bs[lb_r][lb_c] = *(const float4*)(B + (size_t)(k0 + lb_r) * Nd + col0 + lb_c);
        __syncthreads();
        #pragma unroll
        for (int k = 0; k < 16; ++k) {
            float4 a = *(const float4*)&As[k][ty << 2];
            float4 b = *(const float4*)&Bs[k][tx << 2];
            acc[0][0] += a.x * b.x; acc[0][1] += a.x * b.y; acc[0][2] += a.x * b.z; acc[0][3] += a.x * b.w;
            acc[1][0] += a.y * b.x; acc[1][1] += a.y * b.y; acc[1][2] += a.y * b.z; acc[1][3] += a.y * b.w;
            acc[2][0] += a.z * b.x; acc[2][1] += a.z * b.y; acc[2][2] += a.z * b.z; acc[2][3] += a.z * b.w;
            acc[3][0] += a.w * b.x; acc[3][1] += a.w * b.y; acc[3][2] += a.w * b.z; acc[3][3] += a.w * b.w;
        }
    }
    #pragma unroll
    for (int i = 0; i < 4; ++i) {
        int row = row0 + (ty << 2) + i;
        #pragma unroll
        for (int j = 0; j < 4; ++j) {
            int col = col0 + (tx << 2) + j;
            C[(size_t)row * Nd + col] = fmaxf(acc[i][j] + bias[col], 0.f);
        }
    }
}

__global__ void out_kernel(const float* __restrict__ z2, const float* __restrict__ w,
        const float* __restrict__ b, float* __restrict__ out) {
    int idx = blockIdx.x * blockDim.x + threadIdx.x;
    if (idx < NGRAPH * 10) {
        int r = idx / 10, c = idx % 10;
        float s = b[c];
        for (int k = 0; k < 128; ++k) s += z2[r * 128 + k] * w[k * 10 + c];
        out[idx] = fmaxf(s, 0.f);
    }
}

extern "C" void kernel_launch(void* const* d_in, const int* in_sizes, int n_in,
                              void* d_out, int out_size, void* d_ws, size_t ws_size,
                              hipStream_t stream) {
    const float* x    = (const float*)d_in[0];
    const int*   edge = (const int*)d_in[1];
    const int*   esrc = edge;
    const int*   edst = edge + NEDGES;
    const float* wl[4] = {(const float*)d_in[3], (const float*)d_in[6], (const float*)d_in[9],  (const float*)d_in[12]};
    const float* wr[4] = {(const float*)d_in[4], (const float*)d_in[7], (const float*)d_in[10], (const float*)d_in[13]};
    const float* sb[4] = {(const float*)d_in[5], (const float*)d_in[8], (const float*)d_in[11], (const float*)d_in[14]};
    const float* convw = (const float*)d_in[15];
    const float* convb = (const float*)d_in[16];
    const float* l1w   = (const float*)d_in[17];
    const float* l1b   = (const float*)d_in[18];
    const float* l2w   = (const float*)d_in[19];
    const float* l2b   = (const float*)d_in[20];
    const float* ow    = (const float*)d_in[21];
    const float* ob    = (const float*)d_in[22];
    float* out = (float*)d_out;

    char* ws = (char*)d_ws;
    size_t off = 0;
    auto alloc = [&](size_t bytes) -> char* {
        char* p = ws + off;
        off = (off + bytes + 255) & ~(size_t)255;
        return p;
    };
    int*   counts  = (int*)alloc((size_t)NNODES * 4);
    int*   offsets = (int*)alloc((size_t)NNODES * 4);
    int*   cursor  = (int*)alloc((size_t)NNODES * 4);
    int*   loc     = (int*)alloc((size_t)NNODES * 4);
    int*   partial = (int*)alloc(32 * 4);
    float* invdeg  = (float*)alloc((size_t)NNODES * 4);
    int*   ssrc    = (int*)alloc((size_t)NEDGES * 4);
    // SAGE weights in wave-stream layout: per layer 512*K elems (hi + lo bufs)
    _Float16* wch[4]; _Float16* wcl[4];
    for (int l = 0; l < 4; ++l) {
        size_t kb = (size_t)512 * (l ? HID : FIN) * 2;
        wch[l] = (_Float16*)alloc(kb);
        wcl[l] = (_Float16*)alloc(kb);
    }
    _Float16* cvh = (_Float16*)alloc((size_t)HID * 1024 * 2);
    _Float16* cvl = (_Float16*)alloc((size_t)HID * 1024 * 2);

    const size_t H0T = (size_t)NNODES * FIN * 2;        // 8.39 MB
    const size_t AGT = (size_t)NNODES * HID * 2;        // 16.78 MB
    const size_t TKT = (size_t)NGRAPH * KTOP * HID * 2; // 7.86 MB
    const size_t YBT = (size_t)NGRAPH * LOUT * HID * 2; // 7.08 MB
    const size_t YB32T = (size_t)2 * 13824 * 256 * 4;   // 28.3 MB (z1p space)
    const size_t W1T = (size_t)HID * 6912 * 2;          // 3.54 MB

    char* R1 = alloc(2 * H0T);
    char* R2 = alloc(2 * AGT);
    char* R3 = alloc(2 * AGT);
    char* R4 = alloc(2 * AGT);
    // region 1: h0 split (read by fused_sage at its start)
    _Float16* h0h = (_Float16*)R1; _Float16* h0l = (_Float16*)(R1 + H0T);
    // region 4: topk split (written by fused_sage epilogue — MUST NOT alias R1)
    _Float16* tkh = (_Float16*)R4; _Float16* tkl = (_Float16*)(R4 + TKT);
    // region 2+3: tail buffers
    _Float16* ybh = (_Float16*)R2; _Float16* ybl_ = (_Float16*)(R2 + YBT);
    float* z1p  = (float*)(R2 + 2 * YBT);
    char* tail2 = R2 + 2 * YBT + YB32T;
    float* z1  = (float*)tail2;
    float* z2  = (float*)(tail2 + (size_t)NGRAPH * HID * 4);
    _Float16* w1h = (_Float16*)(tail2 + (size_t)NGRAPH * HID * 4 + (size_t)NGRAPH * 128 * 4 + 256);
    _Float16* w1l = (_Float16*)((char*)w1h + W1T);

    // ---- edge prep ----
    hipMemsetAsync(counts, 0, (size_t)NNODES * 4, stream);
    hist_kernel<<<NEDGES / 256, 256, 0, stream>>>(edst, counts);
    scan_block_kernel<<<NNODES / 1024, 1024, 0, stream>>>(counts, loc, partial);
    scan_fixup_kernel<<<NNODES / 1024, 1024, 0, stream>>>(loc, partial, counts, offsets, cursor, invdeg);
    scatter_kernel<<<NEDGES / 256, 256, 0, stream>>>(esrc, edst, cursor, ssrc);

    // ---- merged prep: nan2num + sage weights + conv weight + lin1 weight ----
    PrepAll pa;
    pa.x = x; pa.h0h = h0h; pa.h0l = h0l;
    for (int l = 0; l < 4; ++l) {
        int lk = l ? 8 : 7;
        pa.ps.src[2 * l] = wl[l];     pa.ps.dh[2 * l] = wch[l];     pa.ps.dl[2 * l] = wcl[l];
        pa.ps.src[2 * l + 1] = wr[l]; pa.ps.dh[2 * l + 1] = wch[l]; pa.ps.dl[2 * l + 1] = wcl[l];
        pa.ps.logK[2 * l] = lk;     pa.ps.part[2 * l] = 0;
        pa.ps.logK[2 * l + 1] = lk; pa.ps.part[2 * l + 1] = 1;
    }
    pa.convw = convw; pa.cvh = cvh; pa.cvl = cvl;
    pa.l1w = l1w; pa.w1h = w1h; pa.w1l = w1l;
    prep_all_kernel<<<7600, 256, 0, stream>>>(pa);

    // ---- fused SAGE: all 4 layers + sort-pool/top-k, one kernel ----
    SageWAll swa;
    for (int l = 0; l < 4; ++l) { swa.wh[l] = wch[l]; swa.wl[l] = wcl[l]; swa.bias[l] = sb[l]; }
    fused_sage_all_kernel<<<NGRAPH, 512, 0, stream>>>(
        h0h, h0l, offsets, counts, ssrc, invdeg, swa, tkh, tkl);

    // ---- conv1d as GEMM: M=13824, K=1024, split-K=1, fused bias+relu+split ----
    mfma_ps_kernel<3, 1, 1, 0><<<dim3(108 * 2, 1, 1), 256, 0, stream>>>(
        tkh, tkl, nullptr, nullptr, cvh, cvl, nullptr, nullptr, convb, ybh, ybl_, nullptr, 256, 1024, HID, 108);

    // ---- lin1: M=512, K=6912, split-K=27 partials + reduce ----
    mfma_ps_kernel<3, 0, 1, 1><<<dim3(4 * 2, 1, 27), 256, 0, stream>>>(
        ybh, ybl_, nullptr, nullptr, w1h, w1l, nullptr, nullptr, nullptr, nullptr, nullptr, z1p, 6912, 6912, HID, 4);
    reduce_lin1_kernel<<<NGRAPH * HID / 256, 256, 0, stream>>>(z1p, l1b, z1);

    // ---- lin2: M=512, K=256, N=128 ----
    gemm64_kernel<<<dim3(NGRAPH / 64, 128 / 64), 256, 0, stream>>>(z1, l2w, l2b, z2, HID, HID, 128);

    // ---- out ----
    out_kernel<<<(NGRAPH * 10 + 255) / 256, 256, 0, stream>>>(z2, ow, ob, out);
}

// Round 16
// 412.172 us; speedup vs baseline: 1.0233x; 1.0233x over previous
//
#include <hip/hip_runtime.h>
#include <hip/hip_bf16.h>

#define NNODES 32768
#define NEDGES 524288
#define NGRAPH 512
#define PNODES 64
#define KTOP 30
#define FIN 128
#define HID 256
#define LOUT 27

#define C1F 4.8828125e-4f           // 2^-11
#define C2F 2.384185791015625e-7f   // 2^-22

using f16x8 = __attribute__((ext_vector_type(8))) _Float16;
using f16x4 = __attribute__((ext_vector_type(4))) _Float16;
using f32x4 = __attribute__((ext_vector_type(4))) float;
using f32x16 = __attribute__((ext_vector_type(16))) float;
using u32x4 = __attribute__((ext_vector_type(4))) uint32_t;

template<int N> struct IC { static constexpr int v = N; };

// async global->LDS DMA, 16B per lane, dest = wave-uniform base + lane*16
#define GLDS(src, dst) __builtin_amdgcn_global_load_lds( \
    (const __attribute__((address_space(1))) void*)(src), \
    (__attribute__((address_space(3))) void*)(dst), 16, 0, 0)

// ---------- edge preprocessing ----------
__global__ void hist_kernel(const int* __restrict__ dst, int* __restrict__ counts) {
    int e = blockIdx.x * blockDim.x + threadIdx.x;
    if (e < NEDGES) atomicAdd(&counts[dst[e]], 1);
}

__global__ __launch_bounds__(1024) void scan_block_kernel(const int* __restrict__ counts,
        int* __restrict__ loc, int* __restrict__ partial) {
    int b = blockIdx.x, t = threadIdx.x;
    int i = b * 1024 + t;
    int v = counts[i];
    int lane = t & 63, w = t >> 6;
    int x = v;
    #pragma unroll
    for (int d = 1; d < 64; d <<= 1) { int y = __shfl_up(x, d, 64); if (lane >= d) x += y; }
    __shared__ int ws[16];
    if (lane == 63) ws[w] = x;
    __syncthreads();
    if (w == 0) {
        int s = (lane < 16) ? ws[lane] : 0;
        #pragma unroll
        for (int d = 1; d < 16; d <<= 1) { int y = __shfl_up(s, d, 64); if (lane >= d) s += y; }
        if (lane < 16) ws[lane] = s;
    }
    __syncthreads();
    int base = (w > 0) ? ws[w - 1] : 0;
    int incl = base + x;
    loc[i] = incl - v;
    if (t == 1023) partial[b] = incl;
}

__global__ __launch_bounds__(1024) void scan_fixup_kernel(const int* __restrict__ loc,
        const int* __restrict__ partial, const int* __restrict__ counts,
        int* __restrict__ offsets, int* __restrict__ cursor, float* __restrict__ invdeg) {
    int b = blockIdx.x, t = threadIdx.x;
    int i = b * 1024 + t;
    __shared__ int sbase;
    if (t == 0) { int s = 0; for (int j = 0; j < b; ++j) s += partial[j]; sbase = s; }
    __syncthreads();
    int o = loc[i] + sbase;
    offsets[i] = o;
    cursor[i] = o;
    invdeg[i] = 1.0f / fmaxf((float)counts[i], 1.0f);
}

// ssrc packs (dst_local<<6)|src_local (12 bits) -> direct S-matrix index
__global__ void scatter_kernel(const int* __restrict__ src, const int* __restrict__ dst,
        int* __restrict__ cursor, int* __restrict__ ssrc) {
    int e = blockIdx.x * blockDim.x + threadIdx.x;
    if (e < NEDGES) {
        int d = dst[e];
        int p = atomicAdd(&cursor[d], 1);
        ssrc[p] = ((d & 63) << 6) | (src[e] & 63);
    }
}

// ---------- merged weight/input prep (one launch) ----------
// SAGE weights -> wave-stream fragment order: for wave w, part p (0=Wl,1=Wr),
// chunk (c*2+h2), the 64 lanes' f16x8 fragments are CONTIGUOUS (1KB/chunk).
struct PrepSage {
    const float* src[8];
    _Float16* dh[8];
    _Float16* dl[8];
    int logK[8];
    int part[8];
};

struct PrepAll {
    const float* x;
    _Float16* h0h; _Float16* h0l;
    PrepSage ps;
    const float* convw; _Float16* cvh; _Float16* cvl;
    const float* l1w; _Float16* w1h; _Float16* w1l;
};

// block ranges: [0,4096) nan2num | [4096,6144) sage | [6144,7168) conv | [7168,7600) lin1
__global__ __launch_bounds__(256) void prep_all_kernel(PrepAll P) {
    __shared__ float sh[64][65];
    const int b = blockIdx.x, t = threadIdx.x;
    if (b < 4096) {
        // nan_to_num + split to f16 pair (exact 1,048,576 float4 groups)
        int i = b * 256 + t;
        float4 v = *(const float4*)(P.x + (size_t)i * 4);
        float xs[4] = {v.x, v.y, v.z, v.w};
        f16x4 hh, ll;
        #pragma unroll
        for (int q = 0; q < 4; ++q) {
            float a = xs[q];
            a = (a != a) ? 0.f : a;
            _Float16 h = (_Float16)a;
            hh[q] = h;
            ll[q] = (_Float16)((a - (float)h) * 2048.0f);
        }
        *(f16x4*)(P.h0h + (size_t)i * 4) = hh;
        *(f16x4*)(P.h0l + (size_t)i * 4) = ll;
    } else if (b < 6144) {
        int seg = b - 4096;
        int y = seg >> 8;
        int idx = (seg & 255) * 256 + t;
        int lk = P.ps.logK[y], K = 1 << lk;
        if (idx < 256 * K) {
            int n = idx >> lk, k = idx & (K - 1);
            float w = P.ps.src[y][(size_t)k * 256 + n];
            _Float16 h = (_Float16)w;
            int wv = n >> 5, l31 = n & 31;
            int c = k >> 5, h2 = (k >> 4) & 1, hb = (k >> 3) & 1, j = k & 7;
            int NCH = K >> 5;
            size_t dst = (size_t)(wv * 2 + P.ps.part[y]) * (size_t)(NCH * 1024)
                       + (size_t)(c * 2 + h2) * 512 + (size_t)(hb * 32 + l31) * 8 + j;
            P.ps.dh[y][dst] = h;
            P.ps.dl[y][dst] = (_Float16)((w - (float)h) * 2048.0f);
        }
    } else if (b < 7168) {
        // conv1d weight (o, i, tap) -> [o][k=tap*256+i] split
        int idx = (b - 6144) * 256 + t;
        int o = idx >> 10, k = idx & 1023;
        float w = P.convw[(size_t)o * 1024 + (k & 255) * 4 + (k >> 8)];
        _Float16 h = (_Float16)w;
        P.cvh[(size_t)o * 1024 + k] = h;
        P.cvl[(size_t)o * 1024 + k] = (_Float16)((w - (float)h) * 2048.0f);
    } else {
        // lin1_w [(c*27+l)][n] -> [n][k=l*256+c] f16 split via LDS transpose
        int seg = b - 7168;
        int kb = (seg % 108) * 64;
        int nb = (seg / 108) * 64;
        {
            int kk = t >> 2;
            int nc = (t & 3) * 16;
            int k = kb + kk, l = k >> 8, c = k & 255;
            const float* srow = P.l1w + (size_t)(c * 27 + l) * 256 + nb + nc;
            #pragma unroll
            for (int j = 0; j < 16; j += 4) {
                float4 v = *(const float4*)(srow + j);
                sh[kk][nc + j + 0] = v.x;
                sh[kk][nc + j + 1] = v.y;
                sh[kk][nc + j + 2] = v.z;
                sh[kk][nc + j + 3] = v.w;
            }
        }
        __syncthreads();
        {
            int nn = t >> 2;
            int kc = (t & 3) * 16;
            f16x8 oh[2], ol[2];
            #pragma unroll
            for (int j = 0; j < 16; ++j) {
                float x = sh[kc + j][nn];
                _Float16 h = (_Float16)x;
                oh[j >> 3][j & 7] = h;
                ol[j >> 3][j & 7] = (_Float16)((x - (float)h) * 2048.0f);
            }
            size_t o = (size_t)(nb + nn) * 6912 + kb + kc;
            *(f16x8*)(P.w1h + o) = oh[0];
            *(f16x8*)(P.w1h + o + 8) = oh[1];
            *(f16x8*)(P.w1l + o) = ol[0];
            *(f16x8*)(P.w1l + o + 8) = ol[1];
        }
    }
}

// ---------- fused SAGE: ALL 4 LAYERS + sort-pool/top-k, one graph per block ----------
// v16 = v14 VERBATIM (session best, 413.4us total): fused kernel 179us with
// zero spill (FETCH 19.3MB / WRITE 15.4MB) via the unroll-4 gemmHalf window;
// conv1d keeps split-K=2 + reduce_conv (split-K=1's 216-block grid underfilled
// the 256-CU machine and regressed +8us — occupancy beats traffic here).
struct SageWAll {
    const _Float16* wh[4];
    const _Float16* wl[4];
    const float* bias[4];
};

__global__ __launch_bounds__(512, 2) void fused_sage_all_kernel(
        const _Float16* __restrict__ hh, const _Float16* __restrict__ hl,
        const int* __restrict__ offsets, const int* __restrict__ counts,
        const int* __restrict__ ssrc, const float* __restrict__ invdeg,
        SageWAll W,
        _Float16* __restrict__ tkh, _Float16* __restrict__ tkl) {
    __shared__ __align__(16) _Float16 hp[2][8 * 2048];   // 64 KB h tile (pair)
    __shared__ __align__(16) uint32_t Sw[4096];          // 16 KB counts -> S pair -> sortpool scratch
    const int g = blockIdx.x, t = threadIdx.x;
    const int lane = t & 63, wave = t >> 6;
    const int l31 = lane & 31, hb = lane >> 5;

    // zero S counts
    #pragma unroll
    for (int i = 0; i < 8; ++i) Sw[t + i * 512] = 0;

    // stage h0 (64x128 pair) into chunks 0..3: linear LDS dest, swizzled source
    {
        int a = lane >> 2, b = lane & 3;
        #pragma unroll
        for (int u0 = 0; u0 < 4; ++u0) {
            int u = u0 * 8 + wave;
            int part = u & 1;
            int cs = u >> 1;
            int c = cs >> 2, stripe = cs & 3;
            int row = stripe * 16 + a;
            int o = b ^ ((row >> 1) & 3) ^ (c & 3);
            const _Float16* src = (part ? hl : hh) + (size_t)g * (64 * FIN)
                                + (size_t)row * FIN + c * 32 + o * 8;
            GLDS(src, &hp[part][c * 2048 + stripe * 512]);
        }
    }
    const int gbeg = offsets[g * 64];
    const int gend = offsets[g * 64 + 63] + counts[g * 64 + 63];
    __syncthreads();   // Sw zeroed visible; hp DMA drained

    // build adjacency counts (edge-parallel, ~2 iters)
    for (int e = gbeg + t; e < gend; e += 512)
        atomicAdd(&Sw[ssrc[e] & 4095], 1u);
    __syncthreads();

    // counts -> S pair (aliased over Sw): thread = (row d, octet o)
    {
        int d = t >> 3, o = t & 7;
        float idg = invdeg[g * 64 + d];
        float v[8];
        #pragma unroll
        for (int j = 0; j < 8; ++j) v[j] = (float)Sw[(d << 6) + (o << 3) + j] * idg;
        __syncthreads();
        _Float16* Sp = (_Float16*)Sw;
        f16x8 s0, s1;
        #pragma unroll
        for (int j = 0; j < 8; ++j) {
            _Float16 h1 = (_Float16)v[j];
            s0[j] = h1;
            s1[j] = (_Float16)((v[j] - (float)h1) * 2048.0f);
        }
        int addr = (d << 6) + ((o ^ (d & 7)) << 3);
        *(f16x8*)&Sp[addr] = s0;
        *(f16x8*)&Sp[4096 + addr] = s1;
    }
    __syncthreads();

    const int col = (wave << 5) + l31;

    // one 32-row-half split-pair GEMM over K = NCH*32; depth-2 B prefetch,
    // unroll-4 (bounded scheduler window). Returns folded (a0 + 2^-11 * a1).
    auto gemmHalf = [&](auto NC, const _Float16* __restrict__ Bh,
                        const _Float16* __restrict__ Bl, int rowOff) -> f32x16 {
        constexpr int NIT = decltype(NC)::v * 2;
        const int lo8 = lane << 3;
        f32x16 a0 = 0.f, a1 = 0.f;
        f16x8 bhN = *(const f16x8*)(Bh + lo8);
        f16x8 blN = *(const f16x8*)(Bl + lo8);
        #pragma unroll 4
        for (int it = 0; it < NIT; ++it) {
            const int c = it >> 1, h2 = it & 1;
            f16x8 bh = bhN, bl = blN;
            if (it + 1 < NIT) {
                bhN = *(const f16x8*)(Bh + (it + 1) * 512 + lo8);
                blN = *(const f16x8*)(Bl + (it + 1) * 512 + lo8);
            }
            const int slot = (2 * h2 + hb) ^ ((l31 >> 1) & 3) ^ (c & 3);
            const int addr = rowOff + c * 2048 + (l31 << 5) + (slot << 3);
            f16x8 ah = *(const f16x8*)&hp[0][addr];
            f16x8 al = *(const f16x8*)&hp[1][addr];
            a0 = __builtin_amdgcn_mfma_f32_32x32x16_f16(ah, bh, a0, 0, 0, 0);
            a1 = __builtin_amdgcn_mfma_f32_32x32x16_f16(al, bh, a1, 0, 0, 0);
            a1 = __builtin_amdgcn_mfma_f32_32x32x16_f16(ah, bl, a1, 0, 0, 0);
        }
        return a0 + C1F * a1;
    };

    // pack two floats into hi/lo split-f16 words (bit_cast, no unions)
    auto packpair = [](float x, float y, uint32_t& hw, uint32_t& lw) {
        _Float16 xh = (_Float16)x, yh = (_Float16)y;
        _Float16 xl = (_Float16)((x - (float)xh) * 2048.0f);
        _Float16 yl = (_Float16)((y - (float)yh) * 2048.0f);
        hw = (uint32_t)__builtin_bit_cast(unsigned short, xh)
           | ((uint32_t)__builtin_bit_cast(unsigned short, yh) << 16);
        lw = (uint32_t)__builtin_bit_cast(unsigned short, xl)
           | ((uint32_t)__builtin_bit_cast(unsigned short, yl) << 16);
    };

    // one S.P row-half pass: qf += S[rows]·P (B-frags assembled from pf in-reg)
    auto spass = [&](int soffBase, const f32x16& pf0, const f32x16& pf1, f32x16& qf) {
        const _Float16* Sp = (const _Float16*)Sw;
        f32x16 sA = 0.f, sB = 0.f;
        #pragma unroll
        for (int kc = 0; kc < 4; ++kc) {
            const f32x16& pfk = (kc < 2) ? pf0 : pf1;
            const int i0 = ((2 * kc) & 3) * 4, i1 = ((2 * kc + 1) & 3) * 4;
            float kv0 = hb ? pfk[i1 + 0] : pfk[i0 + 0];
            float kv1 = hb ? pfk[i1 + 1] : pfk[i0 + 1];
            float kv2 = hb ? pfk[i1 + 2] : pfk[i0 + 2];
            float kv3 = hb ? pfk[i1 + 3] : pfk[i0 + 3];
            float sv0 = hb ? pfk[i0 + 0] : pfk[i1 + 0];
            float sv1 = hb ? pfk[i0 + 1] : pfk[i1 + 1];
            float sv2 = hb ? pfk[i0 + 2] : pfk[i1 + 2];
            float sv3 = hb ? pfk[i0 + 3] : pfk[i1 + 3];
            uint32_t kh0, kl0, kh1, kl1, sh0, sl0, sh1, sl1;
            packpair(kv0, kv1, kh0, kl0);
            packpair(kv2, kv3, kh1, kl1);
            packpair(sv0, sv1, sh0, sl0);
            packpair(sv2, sv3, sh1, sl1);
            uint32_t rh0 = (uint32_t)__shfl_xor((int)sh0, 32, 64);
            uint32_t rh1 = (uint32_t)__shfl_xor((int)sh1, 32, 64);
            uint32_t rl0 = (uint32_t)__shfl_xor((int)sl0, 32, 64);
            uint32_t rl1 = (uint32_t)__shfl_xor((int)sl1, 32, 64);
            u32x4 bhu, blu;
            bhu[0] = hb ? rh0 : kh0;  bhu[1] = hb ? rh1 : kh1;
            bhu[2] = hb ? kh0 : rh0;  bhu[3] = hb ? kh1 : rh1;
            blu[0] = hb ? rl0 : kl0;  blu[1] = hb ? rl1 : kl1;
            blu[2] = hb ? kl0 : rl0;  blu[3] = hb ? kl1 : rl1;
            f16x8 bhv = __builtin_bit_cast(f16x8, bhu);
            f16x8 blv = __builtin_bit_cast(f16x8, blu);
            int soff = soffBase + (l31 << 6) + (((2 * kc + hb) ^ (l31 & 7)) << 3);
            f16x8 s0a = *(const f16x8*)&Sp[soff];
            f16x8 s1a = *(const f16x8*)&Sp[4096 + soff];
            sA = __builtin_amdgcn_mfma_f32_32x32x16_f16(s0a, bhv, sA, 0, 0, 0);
            sB = __builtin_amdgcn_mfma_f32_32x32x16_f16(s0a, blv, sB, 0, 0, 0);
            sB = __builtin_amdgcn_mfma_f32_32x32x16_f16(s1a, bhv, sB, 0, 0, 0);
        }
        qf += sA + C1F * sB;
    };

    // one SAGE layer: {sC0,sC1} = relu(S·(H·Wl) + H·Wr + b) for my 32-col slice
    auto run_layer = [&](auto NC, const _Float16* __restrict__ Wsh,
                         const _Float16* __restrict__ Wsl,
                         const float* __restrict__ bias,
                         f32x16& sC0, f32x16& sC1) {
        constexpr size_t wstride = (size_t)decltype(NC)::v * 1024;
        const _Float16* BqH = Wsh + (size_t)((wave << 1) + 1) * wstride;
        const _Float16* BqL = Wsl + (size_t)((wave << 1) + 1) * wstride;
        const _Float16* BpH = Wsh + (size_t)(wave << 1) * wstride;
        const _Float16* BpL = Wsl + (size_t)(wave << 1) * wstride;
        // Q = H·Wr (folded per half)
        f32x16 qf0 = gemmHalf(NC, BqH, BqL, 0);
        f32x16 qf1 = gemmHalf(NC, BqH, BqL, 1024);
        // P = H·Wl (folded per half)
        f32x16 pf0 = gemmHalf(NC, BpH, BpL, 0);
        f32x16 pf1 = gemmHalf(NC, BpH, BpL, 1024);
        // S·P folded straight into qf
        spass(0, pf0, pf1, qf0);        // rows 0..31
        spass(2048, pf0, pf1, qf1);     // rows 32..63
        const float bb = bias[col];
        #pragma unroll
        for (int reg = 0; reg < 16; ++reg) {
            sC0[reg] = fmaxf(qf0[reg] + bb, 0.f);
            sC1[reg] = fmaxf(qf1[reg] + bb, 0.f);
        }
    };

    // re-split sC back into hp as chunk c=wave (input layout for next layer)
    auto hp_write = [&](const f32x16& sC0, const f32x16& sC1) {
        int oc = l31 >> 3, j = l31 & 7;
        #pragma unroll
        for (int mi = 0; mi < 2; ++mi)
            #pragma unroll
            for (int reg = 0; reg < 16; ++reg) {
                int row = (mi << 5) + (reg & 3) + ((reg >> 2) << 3) + (hb << 2);
                int slot = oc ^ ((row >> 1) & 3) ^ (wave & 3);
                int addr = wave * 2048 + (row << 5) + (slot << 3) + j;
                float v = mi ? sC1[reg] : sC0[reg];
                _Float16 h1 = (_Float16)v;
                hp[0][addr] = h1;
                hp[1][addr] = (_Float16)((v - (float)h1) * 2048.0f);
            }
    };

    f32x16 sC0, sC1;
    // layer 0 (K=128)
    run_layer(IC<4>{}, W.wh[0], W.wl[0], W.bias[0], sC0, sC1);
    __syncthreads();   // all reads of hp chunks 0..3 done
    hp_write(sC0, sC1);
    __syncthreads();
    // layer 1 (K=256)
    run_layer(IC<8>{}, W.wh[1], W.wl[1], W.bias[1], sC0, sC1);
    __syncthreads();
    hp_write(sC0, sC1);
    __syncthreads();
    // layer 2 (K=256)
    run_layer(IC<8>{}, W.wh[2], W.wl[2], W.bias[2], sC0, sC1);
    __syncthreads();
    hp_write(sC0, sC1);
    __syncthreads();
    // layer 3 (K=256) + fused sort-pool/top-k epilogue
    run_layer(IC<8>{}, W.wh[3], W.wl[3], W.bias[3], sC0, sC1);
    __syncthreads();   // all waves done reading hp + Sw

    // stage h4 (hi -> hp[0], lo -> hp[1]) as [row][col^swz] f16
    #pragma unroll
    for (int mi = 0; mi < 2; ++mi) {
        #pragma unroll
        for (int reg = 0; reg < 16; ++reg) {
            int row = (mi << 5) + (reg & 3) + ((reg >> 2) << 3) + (hb << 2);
            int cx = col ^ ((((row >> 2) & 1) << 5) | ((row & 3) << 3));
            float v = mi ? sC1[reg] : sC0[reg];
            _Float16 h1 = (_Float16)v;
            hp[0][(row << 8) + cx] = h1;
            hp[1][(row << 8) + cx] = (_Float16)((v - (float)h1) * 2048.0f);
        }
    }
    __syncthreads();

    // sort key = channel 255 of each row (from the stored f16 pair — matches
    // the old sortgather exactly)
    float* vals = (float*)Sw;          // Sw dead after last S·P pass
    int* ords = (int*)(Sw + 64);
    if (t < 64) {
        int sx = 255 ^ ((((t >> 2) & 1) << 5) | ((t & 3) << 3));
        vals[t] = (float)hp[0][(t << 8) + sx] + C1F * (float)hp[1][(t << 8) + sx];
    }
    __syncthreads();
    if (t < 64) {
        float v = vals[t];
        int rank = 0;
        for (int j = 0; j < 64; ++j) {
            float vj = vals[j];
            rank += (vj > v) || (vj == v && j < t);
        }
        if (rank < KTOP) ords[rank] = t;
    }
    __syncthreads();
    // gather top-30 rows straight to tk (f16 pair copied verbatim)
    for (int r = wave; r < KTOP; r += 8) {
        int row = ords[r];
        int cc = (lane & 31) << 3;
        int sx = cc ^ ((((row >> 2) & 1) << 5) | ((row & 3) << 3));
        size_t d = (size_t)(g * KTOP + r) * HID + cc;
        if (lane < 32) *(f16x8*)(tkh + d) = *(const f16x8*)&hp[0][(row << 8) + sx];
        else           *(f16x8*)(tkl + d) = *(const f16x8*)&hp[1][(row << 8) + sx];
    }
}

// ---------- pre-split MFMA GEMM (tail: conv1d-as-GEMM, lin1) ----------
template<int NPROD, int CONV, int NPAIRS, int EPI>
__global__ __launch_bounds__(256, 2) void mfma_ps_kernel(
        const _Float16* __restrict__ A1h, const _Float16* __restrict__ A1l,
        const _Float16* __restrict__ A2h, const _Float16* __restrict__ A2l,
        const _Float16* __restrict__ B1h, const _Float16* __restrict__ B1l,
        const _Float16* __restrict__ B2h, const _Float16* __restrict__ B2l,
        const float* __restrict__ bias,
        _Float16* __restrict__ outh, _Float16* __restrict__ outl,
        float* __restrict__ Cpart,
        int lda, int K, int Nd, int nrb) {
    __shared__ _Float16 As[2][2][128 * 32];   // [buf][term][swizzled 8KB]
    __shared__ _Float16 Bs[2][2][128 * 32];
    const int t = threadIdx.x;
    const int lane = t & 63, wave = t >> 6;
    const int wr = wave & 1, wc = wave >> 1;
    const int bid = blockIdx.x;
    const int rb = bid % nrb, cb = bid / nrb;
    const int row0 = rb * 128, col0 = cb * 128;
    const int l31 = lane & 31, hb = lane >> 5, x3 = l31 & 3;
    const int r16 = lane >> 2;
    const int qsrc8 = ((lane & 3) ^ (r16 & 3)) * 8;   // source k-granule (elems)
    size_t aoffj[2], boffj[2];
    #pragma unroll
    for (int j = 0; j < 2; ++j) {
        int ar = row0 + wave * 32 + j * 16 + r16;
        aoffj[j] = CONV ? ((size_t)ar * 256 + (size_t)(ar / 27) * 768)
                        : (size_t)ar * (size_t)lda;
        boffj[j] = (size_t)(col0 + wave * 32 + j * 16 + r16) * (size_t)K;
    }
    int aroff[2], broff[2], slot8[2];
    #pragma unroll
    for (int mi = 0; mi < 2; ++mi) aroff[mi] = (wr * 64 + mi * 32 + l31) * 32;
    #pragma unroll
    for (int ni = 0; ni < 2; ++ni) broff[ni] = (wc * 64 + ni * 32 + l31) * 32;
    #pragma unroll
    for (int h = 0; h < 2; ++h) slot8[h] = ((2 * h + hb) ^ x3) * 8;

    const int KV = NPAIRS * K;
    const int kchunk = KV / gridDim.z;
    const int kv_lo = blockIdx.z * kchunk, kv_hi = kv_lo + kchunk;

    f32x16 acc0[2][2], acc1[2][2], acc2[2][2];
    #pragma unroll
    for (int i = 0; i < 2; ++i)
        #pragma unroll
        for (int j = 0; j < 2; ++j) { acc0[i][j] = 0.f; acc1[i][j] = 0.f; acc2[i][j] = 0.f; }

    auto stage = [&](int kv, int b) {
        int p = (NPAIRS == 2 && kv >= K) ? 1 : 0;
        int k = kv - p * K;
        const _Float16* __restrict__ sAh = p ? A2h : A1h;
        const _Float16* __restrict__ sAl = p ? A2l : A1l;
        const _Float16* __restrict__ sBh = p ? B2h : B1h;
        const _Float16* __restrict__ sBl = p ? B2l : B1l;
        #pragma unroll
        for (int j = 0; j < 2; ++j) {
            int ldsbase = (wave * 32 + j * 16) * 32;   // elems
            size_t ga = aoffj[j] + k + qsrc8;
            size_t gb = boffj[j] + k + qsrc8;
            GLDS(sAh + ga, &As[b][0][ldsbase]);
            GLDS(sAl + ga, &As[b][1][ldsbase]);
            GLDS(sBh + gb, &Bs[b][0][ldsbase]);
            GLDS(sBl + gb, &Bs[b][1][ldsbase]);
        }
    };

    stage(kv_lo, 0);
    __syncthreads();
    int b = 0;
    for (int kv = kv_lo; kv < kv_hi; kv += 32) {
        if (kv + 32 < kv_hi) stage(kv + 32, b ^ 1);
        #pragma unroll
        for (int h = 0; h < 2; ++h) {
            f16x8 af0[2], af1[2], bf0[2], bf1[2];
            #pragma unroll
            for (int mi = 0; mi < 2; ++mi) {
                af0[mi] = *(const f16x8*)&As[b][0][aroff[mi] + slot8[h]];
                af1[mi] = *(const f16x8*)&As[b][1][aroff[mi] + slot8[h]];
            }
            #pragma unroll
            for (int ni = 0; ni < 2; ++ni) {
                bf0[ni] = *(const f16x8*)&Bs[b][0][broff[ni] + slot8[h]];
                bf1[ni] = *(const f16x8*)&Bs[b][1][broff[ni] + slot8[h]];
            }
            #pragma unroll
            for (int mi = 0; mi < 2; ++mi)
                #pragma unroll
                for (int ni = 0; ni < 2; ++ni) {
                    acc0[mi][ni] = __builtin_amdgcn_mfma_f32_32x32x16_f16(af0[mi], bf0[ni], acc0[mi][ni], 0, 0, 0);
                    acc1[mi][ni] = __builtin_amdgcn_mfma_f32_32x32x16_f16(af1[mi], bf0[ni], acc1[mi][ni], 0, 0, 0);
                    acc1[mi][ni] = __builtin_amdgcn_mfma_f32_32x32x16_f16(af0[mi], bf1[ni], acc1[mi][ni], 0, 0, 0);
                    if (NPROD == 4)
                        acc2[mi][ni] = __builtin_amdgcn_mfma_f32_32x32x16_f16(af1[mi], bf1[ni], acc2[mi][ni], 0, 0, 0);
                }
        }
        b ^= 1;
        __syncthreads();   // prefetch DMA landed during compute; reads done before overwrite
    }

    // C/D: col = lane&31, row = (reg&3) + 8*(reg>>2) + 4*(lane>>5)  [m74/m101]
    const int rquad = 4 * hb;
    #pragma unroll
    for (int ni = 0; ni < 2; ++ni) {
        int col = col0 + wc * 64 + ni * 32 + l31;
        float bb = (EPI == 0) ? bias[col] : 0.f;
        #pragma unroll
        for (int mi = 0; mi < 2; ++mi) {
            #pragma unroll
            for (int reg = 0; reg < 16; ++reg) {
                float v = acc0[mi][ni][reg] + C1F * acc1[mi][ni][reg];
                if (NPROD == 4) v += C2F * acc2[mi][ni][reg];
                int row = row0 + wr * 64 + mi * 32 + (reg & 3) + 8 * (reg >> 2) + rquad;
                if (EPI == 0) {
                    v = fmaxf(v + bb, 0.f);
                    _Float16 h = (_Float16)v;
                    size_t o = (size_t)row * Nd + col;
                    outh[o] = h;
                    outl[o] = (_Float16)((v - (float)h) * 2048.0f);
                } else {
                    size_t zb = (size_t)blockIdx.z * (size_t)(nrb * 128) * Nd;
                    Cpart[zb + (size_t)row * Nd + col] = v;
                }
            }
        }
    }
}

// ---------- conv reduce: sum 2 partials + bias + relu + split ----------
__global__ void reduce_conv_kernel(const float* __restrict__ yb32,
        const float* __restrict__ b, _Float16* __restrict__ ybh, _Float16* __restrict__ ybl) {
    int i = blockIdx.x * 256 + threadIdx.x;   // over 13824*256
    float v = fmaxf(yb32[i] + yb32[i + 13824 * 256] + b[i & 255], 0.f);
    _Float16 h = (_Float16)v;
    ybh[i] = h;
    ybl[i] = (_Float16)((v - (float)h) * 2048.0f);
}

// ---------- lin1 reduce (27 partials) ----------
__global__ void reduce_lin1_kernel(const float* __restrict__ z1p,
        const float* __restrict__ b, float* __restrict__ z1) {
    int i = blockIdx.x * 256 + threadIdx.x;   // 131072
    float s = b[i & 255];
    #pragma unroll
    for (int z = 0; z < 27; ++z) s += z1p[(size_t)z * 131072 + i];
    z1[i] = fmaxf(s, 0.f);
}

// ---------- f32 64x64 GEMM (lin2 only) ----------
__global__ __launch_bounds__(256) void gemm64_kernel(
        const float* __restrict__ A, const float* __restrict__ B,
        const float* __restrict__ bias, float* __restrict__ C,
        int lda, int kend, int Nd) {
    __shared__ float As[16][64];
    __shared__ float Bs[16][64];
    const int tid = threadIdx.x;
    const int tx = tid & 15, ty = tid >> 4;
    const int la_r = tid >> 2, la_c = (tid & 3) << 2;
    const int lb_r = tid >> 4, lb_c = (tid & 15) << 2;
    const int row0 = blockIdx.x * 64, col0 = blockIdx.y * 64;
    const size_t aoff = (size_t)(row0 + la_r) * (size_t)lda;
    float acc[4][4] = {};
    for (int k0 = 0; k0 < kend; k0 += 16) {
        __syncthreads();
        float4 av = *(const float4*)(A + aoff + k0 + la_c);
        As[la_c + 0][la_r] = av.x;
        As[la_c + 1][la_r] = av.y;
        As[la_c + 2][la_r] = av.z;
        As[la_c + 3][la_r] = av.w;
        *(float4*)&Bs[lb_r][lb_c] = *(const float4*)(B + (size_t)(k0 + lb_r) * Nd + col0 + lb_c);
        __syncthreads();
        #pragma unroll
        for (int k = 0; k < 16; ++k) {
            float4 a = *(const float4*)&As[k][ty << 2];
            float4 b = *(const float4*)&Bs[k][tx << 2];
            acc[0][0] += a.x * b.x; acc[0][1] += a.x * b.y; acc[0][2] += a.x * b.z; acc[0][3] += a.x * b.w;
            acc[1][0] += a.y * b.x; acc[1][1] += a.y * b.y; acc[1][2] += a.y * b.z; acc[1][3] += a.y * b.w;
            acc[2][0] += a.z * b.x; acc[2][1] += a.z * b.y; acc[2][2] += a.z * b.z; acc[2][3] += a.z * b.w;
            acc[3][0] += a.w * b.x; acc[3][1] += a.w * b.y; acc[3][2] += a.w * b.z; acc[3][3] += a.w * b.w;
        }
    }
    #pragma unroll
    for (int i = 0; i < 4; ++i) {
        int row = row0 + (ty << 2) + i;
        #pragma unroll
        for (int j = 0; j < 4; ++j) {
            int col = col0 + (tx << 2) + j;
            C[(size_t)row * Nd + col] = fmaxf(acc[i][j] + bias[col], 0.f);
        }
    }
}

__global__ void out_kernel(const float* __restrict__ z2, const float* __restrict__ w,
        const float* __restrict__ b, float* __restrict__ out) {
    int idx = blockIdx.x * blockDim.x + threadIdx.x;
    if (idx < NGRAPH * 10) {
        int r = idx / 10, c = idx % 10;
        float s = b[c];
        for (int k = 0; k < 128; ++k) s += z2[r * 128 + k] * w[k * 10 + c];
        out[idx] = fmaxf(s, 0.f);
    }
}

extern "C" void kernel_launch(void* const* d_in, const int* in_sizes, int n_in,
                              void* d_out, int out_size, void* d_ws, size_t ws_size,
                              hipStream_t stream) {
    const float* x    = (const float*)d_in[0];
    const int*   edge = (const int*)d_in[1];
    const int*   esrc = edge;
    const int*   edst = edge + NEDGES;
    const float* wl[4] = {(const float*)d_in[3], (const float*)d_in[6], (const float*)d_in[9],  (const float*)d_in[12]};
    const float* wr[4] = {(const float*)d_in[4], (const float*)d_in[7], (const float*)d_in[10], (const float*)d_in[13]};
    const float* sb[4] = {(const float*)d_in[5], (const float*)d_in[8], (const float*)d_in[11], (const float*)d_in[14]};
    const float* convw = (const float*)d_in[15];
    const float* convb = (const float*)d_in[16];
    const float* l1w   = (const float*)d_in[17];
    const float* l1b   = (const float*)d_in[18];
    const float* l2w   = (const float*)d_in[19];
    const float* l2b   = (const float*)d_in[20];
    const float* ow    = (const float*)d_in[21];
    const float* ob    = (const float*)d_in[22];
    float* out = (float*)d_out;

    char* ws = (char*)d_ws;
    size_t off = 0;
    auto alloc = [&](size_t bytes) -> char* {
        char* p = ws + off;
        off = (off + bytes + 255) & ~(size_t)255;
        return p;
    };
    int*   counts  = (int*)alloc((size_t)NNODES * 4);
    int*   offsets = (int*)alloc((size_t)NNODES * 4);
    int*   cursor  = (int*)alloc((size_t)NNODES * 4);
    int*   loc     = (int*)alloc((size_t)NNODES * 4);
    int*   partial = (int*)alloc(32 * 4);
    float* invdeg  = (float*)alloc((size_t)NNODES * 4);
    int*   ssrc    = (int*)alloc((size_t)NEDGES * 4);
    // SAGE weights in wave-stream layout: per layer 512*K elems (hi + lo bufs)
    _Float16* wch[4]; _Float16* wcl[4];
    for (int l = 0; l < 4; ++l) {
        size_t kb = (size_t)512 * (l ? HID : FIN) * 2;
        wch[l] = (_Float16*)alloc(kb);
        wcl[l] = (_Float16*)alloc(kb);
    }
    _Float16* cvh = (_Float16*)alloc((size_t)HID * 1024 * 2);
    _Float16* cvl = (_Float16*)alloc((size_t)HID * 1024 * 2);

    const size_t H0T = (size_t)NNODES * FIN * 2;        // 8.39 MB
    const size_t AGT = (size_t)NNODES * HID * 2;        // 16.78 MB
    const size_t TKT = (size_t)NGRAPH * KTOP * HID * 2; // 7.86 MB
    const size_t YBT = (size_t)NGRAPH * LOUT * HID * 2; // 7.08 MB
    const size_t YB32T = (size_t)2 * 13824 * 256 * 4;   // 28.3 MB (2 conv partials)
    const size_t W1T = (size_t)HID * 6912 * 2;          // 3.54 MB

    char* R1 = alloc(2 * H0T);
    char* R2 = alloc(2 * AGT);
    char* R3 = alloc(2 * AGT);
    char* R4 = alloc(2 * AGT);
    // region 1: h0 split (read by fused_sage at its start)
    _Float16* h0h = (_Float16*)R1; _Float16* h0l = (_Float16*)(R1 + H0T);
    // region 4: topk split (written by fused_sage epilogue — MUST NOT alias R1)
    _Float16* tkh = (_Float16*)R4; _Float16* tkl = (_Float16*)(R4 + TKT);
    // region 2+3: tail buffers
    _Float16* ybh = (_Float16*)R2; _Float16* ybl_ = (_Float16*)(R2 + YBT);
    float* yb32 = (float*)(R2 + 2 * YBT);
    float* z1p  = (float*)(R2 + 2 * YBT);   // union: yb32 dead before lin1
    char* tail2 = R2 + 2 * YBT + YB32T;
    float* z1  = (float*)tail2;
    float* z2  = (float*)(tail2 + (size_t)NGRAPH * HID * 4);
    _Float16* w1h = (_Float16*)(tail2 + (size_t)NGRAPH * HID * 4 + (size_t)NGRAPH * 128 * 4 + 256);
    _Float16* w1l = (_Float16*)((char*)w1h + W1T);

    // ---- edge prep ----
    hipMemsetAsync(counts, 0, (size_t)NNODES * 4, stream);
    hist_kernel<<<NEDGES / 256, 256, 0, stream>>>(edst, counts);
    scan_block_kernel<<<NNODES / 1024, 1024, 0, stream>>>(counts, loc, partial);
    scan_fixup_kernel<<<NNODES / 1024, 1024, 0, stream>>>(loc, partial, counts, offsets, cursor, invdeg);
    scatter_kernel<<<NEDGES / 256, 256, 0, stream>>>(esrc, edst, cursor, ssrc);

    // ---- merged prep: nan2num + sage weights + conv weight + lin1 weight ----
    PrepAll pa;
    pa.x = x; pa.h0h = h0h; pa.h0l = h0l;
    for (int l = 0; l < 4; ++l) {
        int lk = l ? 8 : 7;
        pa.ps.src[2 * l] = wl[l];     pa.ps.dh[2 * l] = wch[l];     pa.ps.dl[2 * l] = wcl[l];
        pa.ps.src[2 * l + 1] = wr[l]; pa.ps.dh[2 * l + 1] = wch[l]; pa.ps.dl[2 * l + 1] = wcl[l];
        pa.ps.logK[2 * l] = lk;     pa.ps.part[2 * l] = 0;
        pa.ps.logK[2 * l + 1] = lk; pa.ps.part[2 * l + 1] = 1;
    }
    pa.convw = convw; pa.cvh = cvh; pa.cvl = cvl;
    pa.l1w = l1w; pa.w1h = w1h; pa.w1l = w1l;
    prep_all_kernel<<<7600, 256, 0, stream>>>(pa);

    // ---- fused SAGE: all 4 layers + sort-pool/top-k, one kernel ----
    SageWAll swa;
    for (int l = 0; l < 4; ++l) { swa.wh[l] = wch[l]; swa.wl[l] = wcl[l]; swa.bias[l] = sb[l]; }
    fused_sage_all_kernel<<<NGRAPH, 512, 0, stream>>>(
        h0h, h0l, offsets, counts, ssrc, invdeg, swa, tkh, tkl);

    // ---- conv1d as GEMM: M=13824, K=1024, split-K=2 partials + fused reduce ----
    mfma_ps_kernel<3, 1, 1, 1><<<dim3(108 * 2, 1, 2), 256, 0, stream>>>(
        tkh, tkl, nullptr, nullptr, cvh, cvl, nullptr, nullptr, nullptr, nullptr, nullptr, yb32, 256, 1024, HID, 108);
    reduce_conv_kernel<<<13824 * 256 / 256, 256, 0, stream>>>(yb32, convb, ybh, ybl_);

    // ---- lin1: M=512, K=6912, split-K=27 partials + reduce ----
    mfma_ps_kernel<3, 0, 1, 1><<<dim3(4 * 2, 1, 27), 256, 0, stream>>>(
        ybh, ybl_, nullptr, nullptr, w1h, w1l, nullptr, nullptr, nullptr, nullptr, nullptr, z1p, 6912, 6912, HID, 4);
    reduce_lin1_kernel<<<NGRAPH * HID / 256, 256, 0, stream>>>(z1p, l1b, z1);

    // ---- lin2: M=512, K=256, N=128 ----
    gemm64_kernel<<<dim3(NGRAPH / 64, 128 / 64), 256, 0, stream>>>(z1, l2w, l2b, z2, HID, HID, 128);

    // ---- out ----
    out_kernel<<<(NGRAPH * 10 + 255) / 256, 256, 0, stream>>>(z2, ow, ob, out);
}